// Round 9
// baseline (238.724 us; speedup 1.0000x reference)
//
#include <hip/hip_runtime.h>
#include <hip/hip_bf16.h>

typedef float f4 __attribute__((ext_vector_type(4)));
typedef float f32x4 __attribute__((ext_vector_type(4)));
typedef float f32x16 __attribute__((ext_vector_type(16)));
typedef short s8v __attribute__((ext_vector_type(8)));
typedef unsigned short u16x8 __attribute__((ext_vector_type(8)));

#define BN_EPS   1e-5f
#define PCEN_EPS 1e-6f

// ---- workspace byte layout ----
#define WBF_OFF     0UL
#define WBF_BYTES   (49UL*32*16*2)                 // conv2 W bf16 [tap][co32][k16]
#define WFC1_OFF    51200UL
#define WFC1_BYTES  (208UL*3840*2)                 // fc1 W bf16 padded [208][3840]
#define POOL2_OFF   (WFC1_OFF + WFC1_BYTES)
#define POOL2_BYTES (2048UL*3840*2)                // bf16 [b][3840] (K-padded)

static __device__ inline ushort f2bu(float v) {
    __hip_bfloat16 h = __float2bfloat16(v);
    return *(ushort*)&h;
}

// ---------------------------------------------------------------------------
// K_wprep: conv2 weights fp32 [30][15][7][7] -> bf16 wbf[tap49][co32][k16]
// ---------------------------------------------------------------------------
__global__ __launch_bounds__(256) void k_wprep(
    const float* __restrict__ w2, __hip_bfloat16* __restrict__ wbf)
{
    int i = blockIdx.x*256 + threadIdx.x;
    if (i >= 49*32*16) return;
    int k = i & 15, co = (i >> 4) & 31, tap = i >> 9;
    float v = 0.f;
    if (k < 15 && co < 30)
        v = w2[((co*15 + k)*7 + tap/7)*7 + (tap%7)];
    wbf[i] = __float2bfloat16(v);
}

// ---------------------------------------------------------------------------
// K_A: PCEN + conv1 (MFMA r-shift) + BN/pool/ReLU -> LDS tile
//      + conv2 (MFMA 32x32x16) + BN/pool/ReLU -> pool2b global.
// block = 1 image (2048 x 256). Also converts a 390-elem slice of fc1 weights.
// LDS: img_s 10.3KB + pool1_s 26KB + w1_s 3KB = 39.2KB -> 4 blocks/CU.
// ---------------------------------------------------------------------------
__global__ __launch_bounds__(256, 4) void k_fused_conv(
    const float* __restrict__ x,
    const float* __restrict__ log_s, const float* __restrict__ log_alpha,
    const float* __restrict__ log_delta, const float* __restrict__ log_r,
    const float* __restrict__ w1, const float* __restrict__ cb1,
    const float* __restrict__ g1, const float* __restrict__ be1,
    const float* __restrict__ mu1, const float* __restrict__ va1,
    const ushort* __restrict__ wbfu,
    const float* __restrict__ cb2, const float* __restrict__ g2,
    const float* __restrict__ be2, const float* __restrict__ mu2,
    const float* __restrict__ va2,
    const float* __restrict__ wfc1, __hip_bfloat16* __restrict__ wfc1b,
    __hip_bfloat16* __restrict__ pool2b)
{
    __shared__ ushort img_s[64*72 + 520];   // pcen output, stride 72
    __shared__ ushort pool1_s[12992];       // [h2][y28][x29][c8]
    __shared__ float  w1_s[752];            // conv1 weights fp32

    const int tid = threadIdx.x;
    const int b = blockIdx.x;
    const int l   = tid & 63;
    const int wv  = tid >> 6;
    const int n16 = l & 15;
    const int Q4  = l >> 4;

    // ---- fc1 weight slice conversion (global->global, no sync needed) ----
    {
        int i0 = b * 390;
        for (int j = tid; j < 390; j += 256) {
            int i = i0 + j;
            int n = i / 3840, k = i - n*3840;
            float v = (n < 200 && k < 3630) ? wfc1[(size_t)n*3630 + k] : 0.f;
            wfc1b[i] = __float2bfloat16(v);
        }
    }
    // ---- stage conv1 weights into LDS ----
    for (int i = tid; i < 735; i += 256) w1_s[i] = w1[i];
    // ---- zero pool1_s ci15 pad plane + pool2b K-pad ----
    for (int pz = tid; pz < 784; pz += 256) {
        int yy = pz / 28, xx = pz - yy*28;
        pool1_s[6496 + (yy*29 + xx)*8 + 7] = 0;
    }
    if (tid < 210)
        pool2b[(size_t)b*3840 + 3630 + tid] = __float2bfloat16(0.f);

    // ---- PCEN (parallel segmented scan) -> img_s ----
    {
        const int hrow = tid >> 2, jseg = tid & 3;
        float xs[16];
        const f4* xr = (const f4*)(x + (size_t)b*4096 + hrow*64 + jseg*16);
        f4 v0 = xr[0], v1 = xr[1], v2 = xr[2], v3 = xr[3];
        *(f4*)&xs[0]  = v0; *(f4*)&xs[4]  = v1;
        *(f4*)&xs[8]  = v2; *(f4*)&xs[12] = v3;

        const float s     = __expf(log_s[0]);
        const float alpha = __expf(log_alpha[0]);
        const float delta = __expf(log_delta[0]);
        const float r     = __expf(log_r[0]);
        const float dr    = __expf(r * __logf(delta));
        const float om    = 1.f - s;

        float m = 0.f;
        #pragma unroll
        for (int i = 0; i < 16; ++i) m = om*m + s*xs[i];

        float A16 = om; A16 *= A16; A16 *= A16; A16 *= A16; A16 *= A16;
        float A32 = A16 * A16;

        float v = m;
        float p = __shfl_up(v, 1, 4); v += (jseg >= 1) ? A16*p : 0.f;
        p = __shfl_up(v, 2, 4);       v += (jseg >= 2) ? A32*p : 0.f;
        p = __shfl_up(v, 1, 4);
        float m_in = (jseg >= 1) ? p : 0.f;

        ushort op[16];
        m = m_in;
        #pragma unroll
        for (int i = 0; i < 16; ++i) {
            m = om*m + s*xs[i];
            float t = xs[i] * __expf(-alpha * __logf(m + PCEN_EPS)) + delta;
            op[i] = f2bu(__expf(r * __logf(t)) - dr);
        }
        *(u16x8*)&img_s[hrow*72 + jseg*16]     = *(u16x8*)&op[0];
        *(u16x8*)&img_s[hrow*72 + jseg*16 + 8] = *(u16x8*)&op[8];
    }
    __syncthreads();

    // ---- conv1 B fragments from w1_s (r-shift construction) ----
    s8v Bf[2][4];
    #pragma unroll
    for (int rr = 0; rr < 2; ++rr) {
        #pragma unroll
        for (int ss = 0; ss < 4; ++ss) {
            ushort tmp[8] __attribute__((aligned(16)));
            #pragma unroll
            for (int j = 0; j < 8; ++j) {
                int k = ss*32 + Q4*8 + j;
                int ky = k >> 4, kx = (k & 15) - (wv*2 + rr);
                int kyc = ky < 6 ? ky : 6;
                int kxc = kx < 0 ? 0 : (kx > 6 ? 6 : kx);
                float v = w1_s[n16 < 15 ? (n16*49 + kyc*7 + kxc) : 0];
                bool ok = (ky < 7) && (kx >= 0) && (kx <= 6) && (n16 < 15);
                tmp[j] = ok ? f2bu(v) : (ushort)0;
            }
            Bf[rr][ss] = *(const s8v*)tmp;
        }
    }

    // ---- conv1 MFMA + BN/pool/ReLU -> pool1_s ----
    {
        const int ch = n16;
        float An = 0.f, Bn = 0.f;
        if (ch < 15) {
            An = g1[ch] * rsqrtf(va1[ch] + BN_EPS);
            Bn = (cb1[ch] - mu1[ch]) * An + be1[ch];
        }
        const int h8 = ch >> 3, c8 = ch & 7;
        const int rowA = l & 15;

        #pragma unroll 1
        for (int it = 0; it < 28; ++it) {
            int a  = it % 7;
            int y0 = (it / 7) * 16;

            s8v Aa[4];
            #pragma unroll
            for (int ss = 0; ss < 4; ++ss)
                Aa[ss] = *(const s8v*)&img_s[(y0 + rowA + ss*2 + (Q4 >> 1))*72
                                             + a*8 + (Q4 & 1)*8];

            f32x4 ac0 = (f32x4){0.f,0.f,0.f,0.f};
            f32x4 ac1 = (f32x4){0.f,0.f,0.f,0.f};
            #pragma unroll
            for (int ss = 0; ss < 4; ++ss) {
                ac0 = __builtin_amdgcn_mfma_f32_16x16x32_bf16(Aa[ss], Bf[0][ss], ac0, 0, 0, 0);
                ac1 = __builtin_amdgcn_mfma_f32_16x16x32_bf16(Aa[ss], Bf[1][ss], ac1, 0, 0, 0);
            }

            if (ch < 15 && y0 + Q4*4 < 56) {
                int pxo = a*4 + wv;
                int py  = (y0 >> 1) + Q4*2;
                float v0 = ac0[0]*An + Bn, v1 = ac0[1]*An + Bn;
                float v2 = ac1[0]*An + Bn, v3 = ac1[1]*An + Bn;
                float p0 = fmaxf(fmaxf(fmaxf(v0, v1), fmaxf(v2, v3)), 0.f);
                pool1_s[h8*6496 + (py*29 + pxo)*8 + c8] = f2bu(p0);
                float w0 = ac0[2]*An + Bn, w1v = ac0[3]*An + Bn;
                float w2v = ac1[2]*An + Bn, w3 = ac1[3]*An + Bn;
                float p1 = fmaxf(fmaxf(fmaxf(w0, w1v), fmaxf(w2v, w3)), 0.f);
                pool1_s[h8*6496 + ((py+1)*29 + pxo)*8 + c8] = f2bu(p1);
            }
        }
    }
    __syncthreads();

    // ---- conv2 via mfma_32x32x16: wave = 4 Mfrags, B from global ----
    {
        const int n32 = l & 31;
        const int h2  = l >> 5;

        int Abase[4];
        #pragma unroll
        for (int mf = 0; mf < 4; ++mf) {
            int P  = (wv*4 + mf)*32 + n32;
            int Pc = P < 483 ? P : 483;
            int pr = Pc >> 2, sb = Pc & 3;
            int py = pr / 11, px = pr - py*11;
            int oy = 2*py + (sb >> 1), ox = 2*px + (sb & 1);
            Abase[mf] = (h2*812 + oy*29 + ox) * 16;
        }
        const ushort* Bt = wbfu + n32*16 + h2*8;
        const char* imgc = (const char*)pool1_s;

        f32x16 acc[4];
        #pragma unroll
        for (int mf = 0; mf < 4; ++mf)
            #pragma unroll
            for (int q = 0; q < 16; ++q) acc[mf][q] = 0.f;

        #pragma unroll 1
        for (int ty = 0; ty < 7; ++ty) {
            #pragma unroll
            for (int tx = 0; tx < 7; ++tx) {
                const int tap = ty*7 + tx;
                s8v bfr = *(const s8v*)(Bt + tap*512);
                const int offA = (ty*29 + tx)*16;
                #pragma unroll
                for (int mf = 0; mf < 4; ++mf) {
                    s8v a = *(const s8v*)(imgc + (Abase[mf] + offA));
                    acc[mf] = __builtin_amdgcn_mfma_f32_32x32x16_bf16(a, bfr, acc[mf], 0, 0, 0);
                }
            }
        }

        const int co = n32;
        if (co < 30) {
            float A  = g2[co] * rsqrtf(va2[co] + BN_EPS);
            float Bb = (cb2[co] - mu2[co]) * A + be2[co];
            __hip_bfloat16* outp = pool2b + (size_t)b*3840 + co*121;
            #pragma unroll
            for (int mf = 0; mf < 4; ++mf) {
                #pragma unroll
                for (int g = 0; g < 4; ++g) {
                    int pair = (wv*4 + mf)*8 + 2*g + h2;
                    if (pair < 121) {
                        float v0 = acc[mf][4*g+0]*A + Bb;
                        float v1 = acc[mf][4*g+1]*A + Bb;
                        float v2 = acc[mf][4*g+2]*A + Bb;
                        float v3 = acc[mf][4*g+3]*A + Bb;
                        float pv = fmaxf(fmaxf(fmaxf(v0, v1), fmaxf(v2, v3)), 0.f);
                        outp[pair] = __float2bfloat16(pv);
                    }
                }
            }
        }
    }
}

// ---------------------------------------------------------------------------
// K_B: fc1 + fc2 fused. 128 blocks x 16 rows. 4 waves K-split (960 each,
// 30 steps of 32), LDS reduce, then bias+ReLU+fc2+sigmoid -> out (fp32).
// ---------------------------------------------------------------------------
__global__ __launch_bounds__(256) void k_fc(
    const ushort* __restrict__ Ab, const ushort* __restrict__ Wb,
    const float* __restrict__ fb1, const float* __restrict__ W2,
    const float* __restrict__ fb2, float* __restrict__ out)
{
    __shared__ float red_s[4*16*208];   // 53.2 KB

    const int tid = threadIdx.x;
    const int m0 = blockIdx.x * 16;
    const int wv = tid >> 6, l = tid & 63;
    const int n16 = l & 15, Q4 = l >> 4;
    const int k0 = wv * 960;

    const ushort* Arow = Ab + (size_t)(m0 + n16) * 3840 + k0 + Q4*8;
    const ushort* Wrow = Wb + (size_t)n16 * 3840 + k0 + Q4*8;

    f32x4 acc[13];
    #pragma unroll
    for (int nf = 0; nf < 13; ++nf) acc[nf] = (f32x4){0.f,0.f,0.f,0.f};

    #pragma unroll 1
    for (int t = 0; t < 30; ++t) {
        s8v a = *(const s8v*)(Arow + t*32);
        s8v bf[13];
        #pragma unroll
        for (int nf = 0; nf < 13; ++nf)
            bf[nf] = *(const s8v*)(Wrow + (size_t)nf*16*3840 + t*32);
        #pragma unroll
        for (int nf = 0; nf < 13; ++nf)
            acc[nf] = __builtin_amdgcn_mfma_f32_16x16x32_bf16(a, bf[nf], acc[nf], 0, 0, 0);
    }

    // write partials: C row = Q4*4 + r, col = nf*16 + n16
    #pragma unroll
    for (int nf = 0; nf < 13; ++nf)
        #pragma unroll
        for (int r = 0; r < 4; ++r)
            red_s[(wv*16 + Q4*4 + r)*208 + nf*16 + n16] = acc[nf][r];
    __syncthreads();

    // reduce 4 k-slices + bias + ReLU (each element owned by one thread)
    for (int i = tid; i < 16*208; i += 256) {
        float v = red_s[i] + red_s[16*208 + i] + red_s[2*16*208 + i] + red_s[3*16*208 + i];
        int n = i % 208;
        v += (n < 200) ? fb1[n] : 0.f;
        red_s[i] = fmaxf(v, 0.f);
    }
    __syncthreads();

    // fc2: row = tid>>4, 16 threads per row
    {
        int row = tid >> 4, t16 = tid & 15;
        float a0 = 0.f, a1 = 0.f;
        #pragma unroll
        for (int j = 0; j < 13; ++j) {
            int n = t16 + j*16;
            if (n < 200) {
                float v = red_s[row*208 + n];
                a0 += v * W2[n];
                a1 += v * W2[200 + n];
            }
        }
        #pragma unroll
        for (int mm = 8; mm >= 1; mm >>= 1) {
            a0 += __shfl_xor(a0, mm, 16);
            a1 += __shfl_xor(a1, mm, 16);
        }
        if (t16 == 0) {
            int bi = m0 + row;
            float z0 = a0 + fb2[0], z1 = a1 + fb2[1];
            out[bi*2 + 0] = 1.f / (1.f + expf(-z0));
            out[bi*2 + 1] = 1.f / (1.f + expf(-z1));
        }
    }
}

// ---------------------------------------------------------------------------
extern "C" void kernel_launch(void* const* d_in, const int* in_sizes, int n_in,
                              void* d_out, int out_size, void* d_ws, size_t ws_size,
                              hipStream_t stream)
{
    const float* x         = (const float*)d_in[0];
    const float* log_s     = (const float*)d_in[1];
    const float* log_alpha = (const float*)d_in[2];
    const float* log_delta = (const float*)d_in[3];
    const float* log_r     = (const float*)d_in[4];
    const float* conv1_w   = (const float*)d_in[5];
    const float* conv1_b   = (const float*)d_in[6];
    const float* bn1_g     = (const float*)d_in[7];
    const float* bn1_b     = (const float*)d_in[8];
    const float* bn1_m     = (const float*)d_in[9];
    const float* bn1_v     = (const float*)d_in[10];
    const float* conv2_w   = (const float*)d_in[11];
    const float* conv2_b   = (const float*)d_in[12];
    const float* bn2_g     = (const float*)d_in[13];
    const float* bn2_b     = (const float*)d_in[14];
    const float* bn2_m     = (const float*)d_in[15];
    const float* bn2_v     = (const float*)d_in[16];
    const float* fc1_w     = (const float*)d_in[17];
    const float* fc1_b     = (const float*)d_in[18];
    const float* fc2_w     = (const float*)d_in[19];
    const float* fc2_b     = (const float*)d_in[20];

    char* wsb = (char*)d_ws;
    __hip_bfloat16* wbf    = (__hip_bfloat16*)(wsb + WBF_OFF);
    __hip_bfloat16* wfc1b  = (__hip_bfloat16*)(wsb + WFC1_OFF);
    __hip_bfloat16* pool2b = (__hip_bfloat16*)(wsb + POOL2_OFF);

    k_wprep<<<100, 256, 0, stream>>>(conv2_w, wbf);
    k_fused_conv<<<2048, 256, 0, stream>>>(x, log_s, log_alpha, log_delta, log_r,
                                           conv1_w, conv1_b, bn1_g, bn1_b, bn1_m, bn1_v,
                                           (const ushort*)wbf,
                                           conv2_b, bn2_g, bn2_b, bn2_m, bn2_v,
                                           fc1_w, wfc1b, pool2b);
    k_fc<<<128, 256, 0, stream>>>((const ushort*)pool2b, (const ushort*)wfc1b,
                                  fc1_b, fc2_w, fc2_b, (float*)d_out);
}

// Round 10
// 221.379 us; speedup vs baseline: 1.0784x; 1.0784x over previous
//
#include <hip/hip_runtime.h>
#include <hip/hip_bf16.h>

typedef float f4 __attribute__((ext_vector_type(4)));
typedef float f32x4 __attribute__((ext_vector_type(4)));
typedef float f32x16 __attribute__((ext_vector_type(16)));
typedef short s8v __attribute__((ext_vector_type(8)));
typedef unsigned short u16x8 __attribute__((ext_vector_type(8)));

#define BN_EPS   1e-5f
#define PCEN_EPS 1e-6f

// ---- workspace byte layout ----
#define WBF_OFF     0UL
#define WBF_BYTES   (49UL*32*16*2)                 // conv2 W bf16 [tap][co32][k16]
#define WFC1_OFF    51200UL
#define WFC1_BYTES  (208UL*3840*2)                 // fc1 W bf16 padded [208][3840]
#define POOL2_OFF   (WFC1_OFF + WFC1_BYTES)
#define POOL2_BYTES (2048UL*3840*2)                // bf16 [b][3840] (K-padded)
#define PART_OFF    (POOL2_OFF + POOL2_BYTES)
#define PART_BYTES  (8UL*2048*208*4)               // fp32 [ks8][b][208]

static __device__ inline ushort f2bu(float v) {
    __hip_bfloat16 h = __float2bfloat16(v);
    return *(ushort*)&h;
}

// ---------------------------------------------------------------------------
// K_wprep: conv2 weights fp32 [30][15][7][7] -> bf16 wbf[tap49][co32][k16]
// ---------------------------------------------------------------------------
__global__ __launch_bounds__(256) void k_wprep(
    const float* __restrict__ w2, __hip_bfloat16* __restrict__ wbf)
{
    int i = blockIdx.x*256 + threadIdx.x;
    if (i >= 49*32*16) return;
    int k = i & 15, co = (i >> 4) & 31, tap = i >> 9;
    float v = 0.f;
    if (k < 15 && co < 30)
        v = w2[((co*15 + k)*7 + tap/7)*7 + (tap%7)];
    wbf[i] = __float2bfloat16(v);
}

// ---------------------------------------------------------------------------
// K_A: PCEN + conv1 (MFMA r-shift) + BN/pool/ReLU -> LDS tile
//      + conv2 (MFMA 32x32x16) + BN/pool/ReLU -> pool2b global.
// block = 1 image (2048 x 256). Also converts a 390-elem slice of fc1 weights.
// LDS: img_s 10.3KB + pool1_s 26KB + w1_s 3KB = 39.2KB -> 4 blocks/CU.
// ---------------------------------------------------------------------------
__global__ __launch_bounds__(256, 4) void k_fused_conv(
    const float* __restrict__ x,
    const float* __restrict__ log_s, const float* __restrict__ log_alpha,
    const float* __restrict__ log_delta, const float* __restrict__ log_r,
    const float* __restrict__ w1, const float* __restrict__ cb1,
    const float* __restrict__ g1, const float* __restrict__ be1,
    const float* __restrict__ mu1, const float* __restrict__ va1,
    const ushort* __restrict__ wbfu,
    const float* __restrict__ cb2, const float* __restrict__ g2,
    const float* __restrict__ be2, const float* __restrict__ mu2,
    const float* __restrict__ va2,
    const float* __restrict__ wfc1, __hip_bfloat16* __restrict__ wfc1b,
    __hip_bfloat16* __restrict__ pool2b)
{
    __shared__ ushort img_s[64*72 + 520];   // pcen output, stride 72
    __shared__ ushort pool1_s[12992];       // [h2][y28][x29][c8]
    __shared__ float  w1_s[752];            // conv1 weights fp32

    const int tid = threadIdx.x;
    const int b = blockIdx.x;
    const int l   = tid & 63;
    const int wv  = tid >> 6;
    const int n16 = l & 15;
    const int Q4  = l >> 4;

    // ---- fc1 weight slice conversion (global->global, no sync needed) ----
    {
        int i0 = b * 390;
        for (int j = tid; j < 390; j += 256) {
            int i = i0 + j;
            int n = i / 3840, k = i - n*3840;
            float v = (n < 200 && k < 3630) ? wfc1[(size_t)n*3630 + k] : 0.f;
            wfc1b[i] = __float2bfloat16(v);
        }
    }
    // ---- stage conv1 weights into LDS ----
    for (int i = tid; i < 735; i += 256) w1_s[i] = w1[i];
    // ---- zero pool1_s ci15 pad plane + pool2b K-pad ----
    for (int pz = tid; pz < 784; pz += 256) {
        int yy = pz / 28, xx = pz - yy*28;
        pool1_s[6496 + (yy*29 + xx)*8 + 7] = 0;
    }
    if (tid < 210)
        pool2b[(size_t)b*3840 + 3630 + tid] = __float2bfloat16(0.f);

    // ---- PCEN (parallel segmented scan) -> img_s ----
    {
        const int hrow = tid >> 2, jseg = tid & 3;
        float xs[16];
        const f4* xr = (const f4*)(x + (size_t)b*4096 + hrow*64 + jseg*16);
        f4 v0 = xr[0], v1 = xr[1], v2 = xr[2], v3 = xr[3];
        *(f4*)&xs[0]  = v0; *(f4*)&xs[4]  = v1;
        *(f4*)&xs[8]  = v2; *(f4*)&xs[12] = v3;

        const float s     = __expf(log_s[0]);
        const float alpha = __expf(log_alpha[0]);
        const float delta = __expf(log_delta[0]);
        const float r     = __expf(log_r[0]);
        const float dr    = __expf(r * __logf(delta));
        const float om    = 1.f - s;

        float m = 0.f;
        #pragma unroll
        for (int i = 0; i < 16; ++i) m = om*m + s*xs[i];

        float A16 = om; A16 *= A16; A16 *= A16; A16 *= A16; A16 *= A16;
        float A32 = A16 * A16;

        float v = m;
        float p = __shfl_up(v, 1, 4); v += (jseg >= 1) ? A16*p : 0.f;
        p = __shfl_up(v, 2, 4);       v += (jseg >= 2) ? A32*p : 0.f;
        p = __shfl_up(v, 1, 4);
        float m_in = (jseg >= 1) ? p : 0.f;

        ushort op[16];
        m = m_in;
        #pragma unroll
        for (int i = 0; i < 16; ++i) {
            m = om*m + s*xs[i];
            float t = xs[i] * __expf(-alpha * __logf(m + PCEN_EPS)) + delta;
            op[i] = f2bu(__expf(r * __logf(t)) - dr);
        }
        *(u16x8*)&img_s[hrow*72 + jseg*16]     = *(u16x8*)&op[0];
        *(u16x8*)&img_s[hrow*72 + jseg*16 + 8] = *(u16x8*)&op[8];
    }
    __syncthreads();

    // ---- conv1 B fragments from w1_s (r-shift construction) ----
    s8v Bf[2][4];
    #pragma unroll
    for (int rr = 0; rr < 2; ++rr) {
        #pragma unroll
        for (int ss = 0; ss < 4; ++ss) {
            ushort tmp[8] __attribute__((aligned(16)));
            #pragma unroll
            for (int j = 0; j < 8; ++j) {
                int k = ss*32 + Q4*8 + j;
                int ky = k >> 4, kx = (k & 15) - (wv*2 + rr);
                int kyc = ky < 6 ? ky : 6;
                int kxc = kx < 0 ? 0 : (kx > 6 ? 6 : kx);
                float v = w1_s[n16 < 15 ? (n16*49 + kyc*7 + kxc) : 0];
                bool ok = (ky < 7) && (kx >= 0) && (kx <= 6) && (n16 < 15);
                tmp[j] = ok ? f2bu(v) : (ushort)0;
            }
            Bf[rr][ss] = *(const s8v*)tmp;
        }
    }

    // ---- conv1 MFMA + BN/pool/ReLU -> pool1_s ----
    {
        const int ch = n16;
        float An = 0.f, Bn = 0.f;
        if (ch < 15) {
            An = g1[ch] * rsqrtf(va1[ch] + BN_EPS);
            Bn = (cb1[ch] - mu1[ch]) * An + be1[ch];
        }
        const int h8 = ch >> 3, c8 = ch & 7;
        const int rowA = l & 15;

        #pragma unroll 1
        for (int it = 0; it < 28; ++it) {
            int a  = it % 7;
            int y0 = (it / 7) * 16;

            s8v Aa[4];
            #pragma unroll
            for (int ss = 0; ss < 4; ++ss)
                Aa[ss] = *(const s8v*)&img_s[(y0 + rowA + ss*2 + (Q4 >> 1))*72
                                             + a*8 + (Q4 & 1)*8];

            f32x4 ac0 = (f32x4){0.f,0.f,0.f,0.f};
            f32x4 ac1 = (f32x4){0.f,0.f,0.f,0.f};
            #pragma unroll
            for (int ss = 0; ss < 4; ++ss) {
                ac0 = __builtin_amdgcn_mfma_f32_16x16x32_bf16(Aa[ss], Bf[0][ss], ac0, 0, 0, 0);
                ac1 = __builtin_amdgcn_mfma_f32_16x16x32_bf16(Aa[ss], Bf[1][ss], ac1, 0, 0, 0);
            }

            if (ch < 15 && y0 + Q4*4 < 56) {
                int pxo = a*4 + wv;
                int py  = (y0 >> 1) + Q4*2;
                float v0 = ac0[0]*An + Bn, v1 = ac0[1]*An + Bn;
                float v2 = ac1[0]*An + Bn, v3 = ac1[1]*An + Bn;
                float p0 = fmaxf(fmaxf(fmaxf(v0, v1), fmaxf(v2, v3)), 0.f);
                pool1_s[h8*6496 + (py*29 + pxo)*8 + c8] = f2bu(p0);
                float w0 = ac0[2]*An + Bn, w1v = ac0[3]*An + Bn;
                float w2v = ac1[2]*An + Bn, w3 = ac1[3]*An + Bn;
                float p1 = fmaxf(fmaxf(fmaxf(w0, w1v), fmaxf(w2v, w3)), 0.f);
                pool1_s[h8*6496 + ((py+1)*29 + pxo)*8 + c8] = f2bu(p1);
            }
        }
    }
    __syncthreads();

    // ---- conv2 via mfma_32x32x16: wave = 4 Mfrags, B from global ----
    {
        const int n32 = l & 31;
        const int h2  = l >> 5;

        int Abase[4];
        #pragma unroll
        for (int mf = 0; mf < 4; ++mf) {
            int P  = (wv*4 + mf)*32 + n32;
            int Pc = P < 483 ? P : 483;
            int pr = Pc >> 2, sb = Pc & 3;
            int py = pr / 11, px = pr - py*11;
            int oy = 2*py + (sb >> 1), ox = 2*px + (sb & 1);
            Abase[mf] = (h2*812 + oy*29 + ox) * 16;
        }
        const ushort* Bt = wbfu + n32*16 + h2*8;
        const char* imgc = (const char*)pool1_s;

        f32x16 acc[4];
        #pragma unroll
        for (int mf = 0; mf < 4; ++mf)
            #pragma unroll
            for (int q = 0; q < 16; ++q) acc[mf][q] = 0.f;

        #pragma unroll 1
        for (int ty = 0; ty < 7; ++ty) {
            #pragma unroll
            for (int tx = 0; tx < 7; ++tx) {
                const int tap = ty*7 + tx;
                s8v bfr = *(const s8v*)(Bt + tap*512);
                const int offA = (ty*29 + tx)*16;
                #pragma unroll
                for (int mf = 0; mf < 4; ++mf) {
                    s8v a = *(const s8v*)(imgc + (Abase[mf] + offA));
                    acc[mf] = __builtin_amdgcn_mfma_f32_32x32x16_bf16(a, bfr, acc[mf], 0, 0, 0);
                }
            }
        }

        const int co = n32;
        if (co < 30) {
            float A  = g2[co] * rsqrtf(va2[co] + BN_EPS);
            float Bb = (cb2[co] - mu2[co]) * A + be2[co];
            __hip_bfloat16* outp = pool2b + (size_t)b*3840 + co*121;
            #pragma unroll
            for (int mf = 0; mf < 4; ++mf) {
                #pragma unroll
                for (int g = 0; g < 4; ++g) {
                    int pair = (wv*4 + mf)*8 + 2*g + h2;
                    if (pair < 121) {
                        float v0 = acc[mf][4*g+0]*A + Bb;
                        float v1 = acc[mf][4*g+1]*A + Bb;
                        float v2 = acc[mf][4*g+2]*A + Bb;
                        float v3 = acc[mf][4*g+3]*A + Bb;
                        float pv = fmaxf(fmaxf(fmaxf(v0, v1), fmaxf(v2, v3)), 0.f);
                        outp[pair] = __float2bfloat16(pv);
                    }
                }
            }
        }
    }
}

// ---------------------------------------------------------------------------
// K3a: fc1 bf16 MFMA GEMM. C[2048,208] = A[2048,3840] * W[208,3840]^T.
// grid 256 = 32 Mtiles(64) x 8 Ksplits(480). block 4 waves; wave = 1 Mfrag x
// 13 Nfrags, fragments direct from global (L2-resident), 15 K-steps of 32.
// ---------------------------------------------------------------------------
__global__ __launch_bounds__(256) void k_fc1(
    const ushort* __restrict__ Ab, const ushort* __restrict__ Wb,
    float* __restrict__ part)
{
    const int tid = threadIdx.x;
    const int bid = blockIdx.x;
    const int ks = bid & 7, mt = bid >> 3;
    const int m0 = mt * 64;
    const int k0 = ks * 480;
    const int wv = tid >> 6, l = tid & 63;
    const int n16 = l & 15, Q4 = l >> 4;

    const ushort* Arow = Ab + (size_t)(m0 + wv*16 + n16) * 3840 + k0 + Q4*8;
    const ushort* Wrow = Wb + (size_t)n16 * 3840 + k0 + Q4*8;

    f32x4 acc[13];
    #pragma unroll
    for (int nf = 0; nf < 13; ++nf) acc[nf] = (f32x4){0.f,0.f,0.f,0.f};

    #pragma unroll 1
    for (int t = 0; t < 15; ++t) {
        s8v a = *(const s8v*)(Arow + t*32);
        s8v bf[13];
        #pragma unroll
        for (int nf = 0; nf < 13; ++nf)
            bf[nf] = *(const s8v*)(Wrow + (size_t)nf*16*3840 + t*32);
        #pragma unroll
        for (int nf = 0; nf < 13; ++nf)
            acc[nf] = __builtin_amdgcn_mfma_f32_16x16x32_bf16(a, bf[nf], acc[nf], 0, 0, 0);
    }

    float* dst = part + ((size_t)ks*2048 + m0 + wv*16 + Q4*4) * 208 + n16;
    #pragma unroll
    for (int nf = 0; nf < 13; ++nf)
        #pragma unroll
        for (int r = 0; r < 4; ++r)
            dst[(size_t)r*208 + nf*16] = acc[nf][r];
}

// ---------------------------------------------------------------------------
// K3b: sum 8 partials + bias + ReLU, fc2 + bias + sigmoid -> float32
// ---------------------------------------------------------------------------
__global__ __launch_bounds__(256) void k_fc2(
    const float* __restrict__ part, const float* __restrict__ fb1,
    const float* __restrict__ W2, const float* __restrict__ fb2,
    float* __restrict__ out)
{
    int b = blockIdx.x * 4 + (threadIdx.x >> 6);
    int l = threadIdx.x & 63;
    float a0 = 0.f, a1 = 0.f;
    #pragma unroll
    for (int j = 0; j < 4; ++j) {
        int n = l + j*64;
        if (n < 200) {
            float v = fb1[n];
            #pragma unroll
            for (int ks = 0; ks < 8; ++ks)
                v += part[((size_t)ks*2048 + b)*208 + n];
            v = fmaxf(v, 0.f);
            a0 += v * W2[n];
            a1 += v * W2[200 + n];
        }
    }
    #pragma unroll
    for (int m = 32; m >= 1; m >>= 1) {
        a0 += __shfl_xor(a0, m);
        a1 += __shfl_xor(a1, m);
    }
    if (l == 0) {
        float z0 = a0 + fb2[0], z1 = a1 + fb2[1];
        out[b*2 + 0] = 1.f / (1.f + expf(-z0));
        out[b*2 + 1] = 1.f / (1.f + expf(-z1));
    }
}

// ---------------------------------------------------------------------------
extern "C" void kernel_launch(void* const* d_in, const int* in_sizes, int n_in,
                              void* d_out, int out_size, void* d_ws, size_t ws_size,
                              hipStream_t stream)
{
    const float* x         = (const float*)d_in[0];
    const float* log_s     = (const float*)d_in[1];
    const float* log_alpha = (const float*)d_in[2];
    const float* log_delta = (const float*)d_in[3];
    const float* log_r     = (const float*)d_in[4];
    const float* conv1_w   = (const float*)d_in[5];
    const float* conv1_b   = (const float*)d_in[6];
    const float* bn1_g     = (const float*)d_in[7];
    const float* bn1_b     = (const float*)d_in[8];
    const float* bn1_m     = (const float*)d_in[9];
    const float* bn1_v     = (const float*)d_in[10];
    const float* conv2_w   = (const float*)d_in[11];
    const float* conv2_b   = (const float*)d_in[12];
    const float* bn2_g     = (const float*)d_in[13];
    const float* bn2_b     = (const float*)d_in[14];
    const float* bn2_m     = (const float*)d_in[15];
    const float* bn2_v     = (const float*)d_in[16];
    const float* fc1_w     = (const float*)d_in[17];
    const float* fc1_b     = (const float*)d_in[18];
    const float* fc2_w     = (const float*)d_in[19];
    const float* fc2_b     = (const float*)d_in[20];

    char* wsb = (char*)d_ws;
    __hip_bfloat16* wbf    = (__hip_bfloat16*)(wsb + WBF_OFF);
    __hip_bfloat16* wfc1b  = (__hip_bfloat16*)(wsb + WFC1_OFF);
    __hip_bfloat16* pool2b = (__hip_bfloat16*)(wsb + POOL2_OFF);
    float* part            = (float*)(wsb + PART_OFF);

    k_wprep<<<100, 256, 0, stream>>>(conv2_w, wbf);
    k_fused_conv<<<2048, 256, 0, stream>>>(x, log_s, log_alpha, log_delta, log_r,
                                           conv1_w, conv1_b, bn1_g, bn1_b, bn1_m, bn1_v,
                                           (const ushort*)wbf,
                                           conv2_b, bn2_g, bn2_b, bn2_m, bn2_v,
                                           fc1_w, wfc1b, pool2b);
    k_fc1<<<256, 256, 0, stream>>>((const ushort*)pool2b, (const ushort*)wfc1b, part);
    k_fc2<<<512, 256, 0, stream>>>(part, fc1_b, fc2_w, fc2_b, (float*)d_out);
}